// Round 13
// baseline (187.240 us; speedup 1.0000x reference)
//
#include <hip/hip_runtime.h>
#include <hip/hip_bf16.h>
#include <cstdint>

// Problem constants (from reference): B=2, M=256, D=256, DE=64
#define BB 2
#define MM 256
#define DD 256
#define DE 64
#define K2 (2*MM)      // 512
#define WM_LD (DD+DE)  // 320, Wm row stride
#define WH_LD (2*DD)   // 512, Wh row stride
#define DEP_LD 68      // padded depsh row (floats)

// e4-blocked transposed weights: X4[e4*DD + d] = {X[d][4e4+0..3]} (float4)
__device__ float4 g_Wz4   [64*DD];   // Wz   (256x256)
__device__ float4 g_Wm4   [64*DD];   // Wm[:,DE:] (256x256)
__device__ float4 g_WmDep4[16*DD];   // Wm[:,:DE] (256x64)
__device__ float4 g_Wh4lo [64*DD];   // Wh[:,:256]
__device__ float4 g_Wh4hi [64*DD];   // Wh[:,256:]
// Intermediates
__device__ float g_fproj [BB*MM*DD]; // f @ Wm_f.T
__device__ float g_fnf   [BB*MM];    // f . wa_nf
__device__ float g_aspdot[MM];       // asp . wa_asp   (asp rows only)
__device__ float g_asph  [MM*DD];    // asp @ Wh[:,D:].T (asp rows only)
__device__ int   g_done;             // pre-completion counter (reset by k_tr)

// ------------------------------------------------ LDS-tiled transposes + copy
__global__ __launch_bounds__(256) void k_tr(const float* __restrict__ Wz,
                                            const float* __restrict__ Wm,
                                            const float* __restrict__ Wh,
                                            const float4* __restrict__ src,
                                            float4* __restrict__ dst, int n4) {
  const int t = threadIdx.x, blk = blockIdx.x;
  if (blk == 0 && t == 0) g_done = 0;          // reset flag for k_main (every call)
  const int c = t & 63, r0 = t >> 6;
  __shared__ float tile[64][65];

  // feature copy (independent; issue first)
  const int gidx = blk*256 + t;
  if (gidx < n4) dst[gidx] = src[gidx];

  const float* s = nullptr; float4* d4 = nullptr;
  int ld = 0, row0 = 0, col0 = 0, e4base = 0;
  if (blk < 16)      { s = Wz; ld = DD;    row0 = (blk>>2)*64; col0 = (blk&3)*64;      d4 = g_Wz4;    e4base = (blk&3)*16; }
  else if (blk < 32) { int x = blk-16; s = Wm; ld = WM_LD; row0 = (x>>2)*64; col0 = DE + (x&3)*64; d4 = g_Wm4; e4base = (x&3)*16; }
  else if (blk < 36) { int x = blk-32; s = Wm; ld = WM_LD; row0 = x*64;      col0 = 0;             d4 = g_WmDep4; e4base = 0; }
  else if (blk < 68) { int x = blk-36; int rt = x>>3, cg = x&7; s = Wh; ld = WH_LD; row0 = rt*64; col0 = cg*64;
                       d4 = (cg < 4) ? g_Wh4lo : g_Wh4hi; e4base = (cg&3)*16; }
  if (s) {
    #pragma unroll
    for (int rr = r0; rr < 64; rr += 4)
      tile[rr][c] = s[(size_t)(row0 + rr)*ld + col0 + c];
    __syncthreads();
    #pragma unroll
    for (int je = r0; je < 16; je += 4)
      d4[(size_t)(e4base + je)*DD + row0 + c] =
        make_float4(tile[c][4*je+0], tile[c][4*je+1], tile[c][4*je+2], tile[c][4*je+3]);
  }
}

// ------------------------------------------------ merged: pre (blocks 32..287)
// + attn (blocks 0..31). Attn does its pre-independent work first, then
// acquire-spins on g_done (released by pre blocks) before the dependent phases.
struct PreSM  { float fin[2][DD]; float fzsh[2][DD]; };
struct AttnSM {
  int   act[K2];
  float sv [K2];
  int   wcnt[8];
  float wrm[4], wrs[4];
  float wadep[DE];
  float fnfsh[MM];
  float depsh[64*DEP_LD];
  float fused_sh[DD];
};
union SMem { PreSM pre; AttnSM attn; };

__global__ __launch_bounds__(256, 1) void k_main(const float* __restrict__ feats,
                                                 const float* __restrict__ bz,
                                                 const float* __restrict__ Wa,
                                                 const int*   __restrict__ a_start,
                                                 const int*   __restrict__ a_end,
                                                 const float* __restrict__ dta,
                                                 const int*   __restrict__ adj,
                                                 float* __restrict__ out) {
  __shared__ SMem sm;
  const int blk = blockIdx.x;
  const int t = threadIdx.x;
  const int lane = t & 63, wv = t >> 6;

  if (blk >= 32) {
    // ================= PRE path: 2 rows per block =================
    PreSM& P = sm.pre;
    const int p  = blk - 32;           // 0..255
    const int b  = p >> 7;
    const int m0 = (p & 127) * 2;

    P.fin[0][t] = feats[((size_t)b*(MM+1) + m0 + 1)*DD + t];
    P.fin[1][t] = feats[((size_t)b*(MM+1) + m0 + 2)*DD + t];
    __syncthreads();

    float a0 = 0.f, a1 = 0.f;
    #pragma unroll 8
    for (int e4 = 0; e4 < 64; ++e4) {
      const float4 w  = g_Wz4[(size_t)e4*DD + t];
      const float4 f0 = *(const float4*)&P.fin[0][e4*4];
      const float4 f1 = *(const float4*)&P.fin[1][e4*4];
      a0 += f0.x*w.x + f0.y*w.y + f0.z*w.z + f0.w*w.w;
      a1 += f1.x*w.x + f1.y*w.y + f1.z*w.z + f1.w*w.w;
    }
    const float bzt = bz[t];
    P.fzsh[0][t] = a0 + bzt; P.fzsh[1][t] = a1 + bzt;
    __syncthreads();

    const int s0 = a_start[0], e0 = a_end[0], s1 = a_start[1], e1 = a_end[1];
    if (wv < 2) {            // fnf rows 0,1
      float pp = 0.f;
      for (int e = lane; e < DD; e += 64) pp += P.fzsh[wv][e] * Wa[DE + e];
      for (int off = 32; off > 0; off >>= 1) pp += __shfl_down(pp, off, 64);
      if (lane == 0) g_fnf[b*MM + m0 + wv] = pp;
    } else if (b == 0) {     // aspdot rows 0,1 (asp rows only)
      const int rr = wv - 2;
      const int ri = m0 + rr;
      if ((ri >= s0 && ri < e0) || (ri >= s1 && ri < e1)) {
        float pp = 0.f;
        for (int e = lane; e < DD; e += 64) pp += P.fzsh[rr][e] * Wa[DE + DD + e];
        for (int off = 32; off > 0; off >>= 1) pp += __shfl_down(pp, off, 64);
        if (lane == 0) g_aspdot[ri] = pp;
      }
    }

    float p0 = 0.f, p1 = 0.f;
    #pragma unroll 8
    for (int e4 = 0; e4 < 64; ++e4) {
      const float4 w  = g_Wm4[(size_t)e4*DD + t];
      const float4 f0 = *(const float4*)&P.fzsh[0][e4*4];
      const float4 f1 = *(const float4*)&P.fzsh[1][e4*4];
      p0 += f0.x*w.x + f0.y*w.y + f0.z*w.z + f0.w*w.w;
      p1 += f1.x*w.x + f1.y*w.y + f1.z*w.z + f1.w*w.w;
    }
    g_fproj[((size_t)b*MM + m0    )*DD + t] = p0;
    g_fproj[((size_t)b*MM + m0 + 1)*DD + t] = p1;

    if (b == 0) {            // asph only for asp rows
      const bool need0 = ((m0   >= s0 && m0   < e0) || (m0   >= s1 && m0   < e1));
      const bool need1 = ((m0+1 >= s0 && m0+1 < e0) || (m0+1 >= s1 && m0+1 < e1));
      if (need0 || need1) {
        float q0 = 0.f, q1 = 0.f;
        #pragma unroll 8
        for (int e4 = 0; e4 < 64; ++e4) {
          const float4 w  = g_Wh4hi[(size_t)e4*DD + t];
          const float4 f0 = *(const float4*)&P.fzsh[0][e4*4];
          const float4 f1 = *(const float4*)&P.fzsh[1][e4*4];
          q0 += f0.x*w.x + f0.y*w.y + f0.z*w.z + f0.w*w.w;
          q1 += f1.x*w.x + f1.y*w.y + f1.z*w.z + f1.w*w.w;
        }
        if (need0) g_asph[(size_t)(m0    )*DD + t] = q0;
        if (need1) g_asph[(size_t)(m0 + 1)*DD + t] = q1;
      }
    }

    // signal completion (device-scope release; cross-XCD safe)
    __syncthreads();
    __threadfence();
    if (t == 0)
      __hip_atomic_fetch_add(&g_done, 1, __ATOMIC_RELEASE, __HIP_MEMORY_SCOPE_AGENT);
    return;
  }

  // ================= ATTN path: one block per updated row =================
  AttnSM& A = sm.attn;
  const int b = blk >> 4;
  const int r = blk & 15;
  const int i = a_start[b] + r;
  if (i >= a_end[b] || i >= MM) return;   // block-uniform
  const int d = t;

  // ---- Phase A (independent of pre): adj, compaction, dta dots, depsh
  const int mval0 = adj[((size_t)b*MM + i)*MM + t];          // row (coalesced)
  const int mval1 = adj[((size_t)b*MM + t)*MM + i];          // col (gather)
  float4 wm4[16];                                            // Wm_dep row d (from k_tr)
  #pragma unroll
  for (int e4 = 0; e4 < 16; ++e4) wm4[e4] = g_WmDep4[(size_t)e4*DD + d];
  if (t < DE) A.wadep[t] = Wa[t];

  const bool on0 = (mval0 != 0);
  const bool on1 = (mval1 != 0);
  const unsigned long long b0 = __ballot(on0);
  const unsigned long long b1 = __ballot(on1);
  if (lane == 0) { A.wcnt[wv] = __popcll(b0); A.wcnt[4+wv] = __popcll(b1); }
  __syncthreads();                                   // S1
  const int tot0 = A.wcnt[0] + A.wcnt[1] + A.wcnt[2] + A.wcnt[3];
  const int na   = tot0 + A.wcnt[4] + A.wcnt[5] + A.wcnt[6] + A.wcnt[7];
  {
    int off0 = 0, off1 = tot0;
    for (int w2 = 0; w2 < wv; ++w2) { off0 += A.wcnt[w2]; off1 += A.wcnt[4+w2]; }
    off0 += __popcll(b0 & ((1ull << lane) - 1ull));
    off1 += __popcll(b1 & ((1ull << lane) - 1ull));
    if (on0) A.act[off0] = t;
    if (on1) A.act[off1] = MM + t;
  }
  __syncthreads();                                   // S2: act

  // s-phase: 4 threads per active k -> RAW dot into sv; stages chunk-0 depsh
  const int jj = t >> 2, sub = t & 3;
  for (int base = 0; base < na; base += 64) {
    const int j = base + jj;
    float p = 0.f;
    if (j < na) {
      const int k = A.act[j];
      const float* dv = (k < MM) ? dta + (((size_t)b*MM + i)*MM + k)*DE
                                 : dta + (((size_t)b*MM + (k - MM))*MM + i)*DE;
      const float4* dv4 = (const float4*)dv + sub*4;
      const float4 v0 = dv4[0], v1 = dv4[1], v2 = dv4[2], v3 = dv4[3];
      const float* wa = A.wadep + sub*16;
      p = v0.x*wa[0]  + v0.y*wa[1]  + v0.z*wa[2]  + v0.w*wa[3]
        + v1.x*wa[4]  + v1.y*wa[5]  + v1.z*wa[6]  + v1.w*wa[7]
        + v2.x*wa[8]  + v2.y*wa[9]  + v2.z*wa[10] + v2.w*wa[11]
        + v3.x*wa[12] + v3.y*wa[13] + v3.z*wa[14] + v3.w*wa[15];
      if (base == 0) {
        float4* ds = (float4*)(A.depsh + jj*DEP_LD + sub*16);
        ds[0] = v0; ds[1] = v1; ds[2] = v2; ds[3] = v3;
      }
    }
    p += __shfl_xor(p, 1, 64);
    p += __shfl_xor(p, 2, 64);
    if (j < na && sub == 0) A.sv[j] = p;             // raw; fnf/aspdot deferred
  }

  // ---- wait for pre blocks (acquire; invalidates this XCD's L2)
  if (t == 0) {
    while (__hip_atomic_load(&g_done, __ATOMIC_ACQUIRE, __HIP_MEMORY_SCOPE_AGENT) < 256) {
      __builtin_amdgcn_s_sleep(16);
    }
  }
  __syncthreads();                                   // S3: sv/depsh + flag

  // ---- Phase B: dependent loads
  A.fnfsh[t] = g_fnf[b*MM + t];
  const float aspdot_i = g_aspdot[i];
  const float asph_i   = g_asph[(size_t)i*DD + d];
  __syncthreads();                                   // S4: fnfsh

  // finalize s (same FP order as before: p + fnf + aspdot, then leaky)
  for (int j = t; j < na; j += 256) {
    const float s = A.sv[j] + A.fnfsh[A.act[j] & (MM-1)] + aspdot_i;
    A.sv[j] = (s > 0.f) ? s : 0.01f * s;
  }
  __syncthreads();                                   // S5

  // softmax over active
  {
    float part = -3.4e38f;
    for (int j = t; j < na; j += 256) part = fmaxf(part, A.sv[j]);
    for (int off = 32; off > 0; off >>= 1) part = fmaxf(part, __shfl_down(part, off, 64));
    if (lane == 0) A.wrm[wv] = part;
  }
  __syncthreads();                                   // S6
  const float mx = fmaxf(fmaxf(A.wrm[0], A.wrm[1]), fmaxf(A.wrm[2], A.wrm[3]));
  {
    float psum = 0.f;
    for (int j = t; j < na; j += 256) { float e = expf(A.sv[j] - mx); A.sv[j] = e; psum += e; }
    for (int off = 32; off > 0; off >>= 1) psum += __shfl_down(psum, off, 64);
    if (lane == 0) A.wrs[wv] = psum;
  }
  __syncthreads();                                   // S7
  const float inv = 1.f / (A.wrs[0] + A.wrs[1] + A.wrs[2] + A.wrs[3]);
  for (int j = t; j < na; j += 256) A.sv[j] *= inv;
  __syncthreads();                                   // S8: normalized sv

  // fused[d] = sum_k w_k * relu(dep_k . Wm_dep[d] + fproj[b,k%M,d])
  float acc = 0.f;
  for (int base = 0; base < na; base += 64) {
    const int cnt = min(64, na - base);
    if (base > 0) {                                  // rare: na > 64 — restage depsh
      __syncthreads();
      for (int q = t; q < cnt*16; q += 256) {
        const int jl = q >> 4, e4 = q & 15;
        const int k = A.act[base + jl];
        const float* dv = (k < MM) ? dta + (((size_t)b*MM + i)*MM + k)*DE
                                   : dta + (((size_t)b*MM + (k - MM))*MM + i)*DE;
        *(float4*)(A.depsh + jl*DEP_LD + e4*4) = ((const float4*)dv)[e4];
      }
      __syncthreads();
    }
    #pragma unroll 4
    for (int jl = 0; jl < cnt; ++jl) {
      const float4* dp = (const float4*)(A.depsh + jl*DEP_LD);
      float dot = 0.f;
      #pragma unroll
      for (int e4 = 0; e4 < 16; ++e4) {
        const float4 v = dp[e4];
        const float4 w = wm4[e4];
        dot += v.x*w.x + v.y*w.y + v.z*w.z + v.w*w.w;
      }
      const int k = A.act[base + jl];
      float msg = dot + g_fproj[((size_t)b*MM + (k & (MM-1)))*DD + d];
      msg = (msg > 0.f) ? msg : 0.f;
      acc += A.sv[base + jl] * msg;
    }
  }
  A.fused_sh[d] = acc;
  __syncthreads();                                   // S9

  // out = relu(fused @ Wh[:,:D].T + asph_i)  via float4 Wh4lo streams
  float o = asph_i;
  #pragma unroll 8
  for (int e4 = 0; e4 < 64; ++e4) {
    const float4 w = g_Wh4lo[(size_t)e4*DD + d];
    const float4 f = *(const float4*)&A.fused_sh[e4*4];
    o += f.x*w.x + f.y*w.y + f.z*w.z + f.w*w.w;
  }
  out[((size_t)b*(MM+1) + i + 1)*DD + d] = (o > 0.f) ? o : 0.f;
}

extern "C" void kernel_launch(void* const* d_in, const int* in_sizes, int n_in,
                              void* d_out, int out_size, void* d_ws, size_t ws_size,
                              hipStream_t stream) {
  const float* feats   = (const float*)d_in[0];
  const float* dta     = (const float*)d_in[1];
  const int*   adj     = (const int*)  d_in[2];
  const int*   a_start = (const int*)  d_in[3];
  const int*   a_end   = (const int*)  d_in[4];
  const float* Wz      = (const float*)d_in[5];
  const float* bz      = (const float*)d_in[6];
  const float* Wa      = (const float*)d_in[7];
  const float* Wm      = (const float*)d_in[8];
  const float* Wh      = (const float*)d_in[9];
  float* out = (float*)d_out;

  const int n4 = BB*(MM+1)*DD/4;  // 32896 float4
  k_tr  <<<132, 256, 0, stream>>>(Wz, Wm, Wh, (const float4*)feats, (float4*)out, n4);
  k_main<<<288, 256, 0, stream>>>(feats, bz, Wa, a_start, a_end, dta, adj, out);
}